// Round 1
// baseline (440.010 us; speedup 1.0000x reference)
//
#include <hip/hip_runtime.h>

// GQA causal+segment-masked flash attention. fp32 in/out.
// B=2, T=2048, NQ=32 (8 kv heads x 4), D=128.
// R8: swapped QK (mfma(K,Q)) -> P is lane-local per q-row; P transpose done
// in-register via cvt_pk_bf16 + permlane16/32_swap (sP LDS removed -> 32KB LDS
// -> 5 blocks/CU). V swizzle fixed to sc^((d>>1)&3) for conflict-free
// ds_read_b128. setprio(1) around MFMA clusters.

typedef __bf16 bf16x8 __attribute__((ext_vector_type(8)));
typedef __bf16 bf16x2 __attribute__((ext_vector_type(2)));
typedef _Float16 f16x8 __attribute__((ext_vector_type(8)));
typedef float f32x4 __attribute__((ext_vector_type(4)));
typedef unsigned int uint2v __attribute__((ext_vector_type(2)));

#define B_   2
#define T_   2048
#define NQ_  32
#define NKV_ 8
#define D_   128

#define MASKV (-3.0e38f)
#define LOG2E 1.44269504f
#define TILE_US 8192           // ushorts per 32-col KV tile in ws: 8KB fp16 K + 8KB bf16 Vt
#define WS_TILES_BYTES ((size_t)B_ * NKV_ * (T_ / 32) * TILE_US * 2)   // 16777216
#define WS_NEED (WS_TILES_BYTES + (size_t)B_ * T_ * 4)

static __device__ __forceinline__ unsigned short f2bf(float x) {
    union { float f; unsigned int u; } c; c.f = x;
    unsigned int r = c.u + 0x7fffu + ((c.u >> 16) & 1u);
    return (unsigned short)(r >> 16);
}

union U8  { unsigned short us[8]; bf16x8 v; };
union H8  { _Float16 h[8]; f16x8 v; };
union PKW { bf16x2 h; unsigned int u; };
union PA4 { unsigned int u[4]; bf16x8 v; };

static __device__ __forceinline__ void dma16(const unsigned short* g, unsigned short* l) {
    __builtin_amdgcn_global_load_lds(
        (const __attribute__((address_space(1))) unsigned int*)g,
        (__attribute__((address_space(3))) unsigned int*)l, 16, 0, 0);
}

// register-pair lane swaps (gfx950): a[32:63] <-> b[0:31]  /  a[16:31]<->b[0:15], a[48:63]<->b[32:47]
static __device__ __forceinline__ void pl32swap(unsigned int& a, unsigned int& b) {
#if __has_builtin(__builtin_amdgcn_permlane32_swap)
    uint2v t = __builtin_amdgcn_permlane32_swap(a, b, false, false);
    a = t.x; b = t.y;
#else
    asm("s_nop 1\n\tv_permlane32_swap_b32 %0, %1" : "+v"(a), "+v"(b));
#endif
}
static __device__ __forceinline__ void pl16swap(unsigned int& a, unsigned int& b) {
#if __has_builtin(__builtin_amdgcn_permlane16_swap)
    uint2v t = __builtin_amdgcn_permlane16_swap(a, b, false, false);
    a = t.x; b = t.y;
#else
    asm("s_nop 1\n\tv_permlane16_swap_b32 %0, %1" : "+v"(a), "+v"(b));
#endif
}

// ---------------- prep 1: K -> fp16, V^T -> bf16, swizzled ws tiles ----------------
__global__ __launch_bounds__(256)
void prep(const float* __restrict__ kg, const float* __restrict__ vg,
          unsigned short* __restrict__ ws)
{
    const int tid = threadIdx.x;
    const int st  = blockIdx.x;    // 32-col KV tile index
    const int kvh = blockIdx.y;
    const int b   = blockIdx.z;
    unsigned short* base = ws + ((size_t)((b * NKV_ + kvh) * (T_ / 32) + st)) * TILE_US;

    // K: 512 tasks = 32 rows x 16 chunks(8 elems), fp16
    #pragma unroll
    for (int it = 0; it < 2; ++it) {
        int task = tid + it * 256;
        int r = task >> 4, c = task & 15;
        const float* kp = kg + (((size_t)(b * T_ + st * 32 + r)) * NKV_ + kvh) * D_ + c * 8;
        H8 hu;
        #pragma unroll
        for (int j = 0; j < 8; ++j) hu.h[j] = (_Float16)kp[j];
        int slot = r * 16 + (c ^ (r & 7));
        *(f16x8*)(base + slot * 8) = hu.v;
    }
    // V^T: 512 tasks = 128 d x 4 s-chunks(8 s), bf16
    // swizzle sc ^ ((d>>1)&3): 8 consecutive lanes (d) hit 8 distinct 16B slots
    #pragma unroll
    for (int it = 0; it < 2; ++it) {
        int task = tid + it * 256;
        int d = task & 127, sc = task >> 7;
        const float* vp = vg + (((size_t)(b * T_ + st * 32 + sc * 8)) * NKV_ + kvh) * D_ + d;
        U8 pk;
        #pragma unroll
        for (int j = 0; j < 8; ++j) pk.us[j] = f2bf(vp[j * (NKV_ * D_)]);
        int slot = d * 4 + (sc ^ ((d >> 1) & 3));
        *(bf16x8*)(base + 4096 + slot * 8) = pk.v;
    }
}

// ---------------- prep 2: per-row segment start indices ----------------
__global__ __launch_bounds__(256)
void prep_sstart(const int* __restrict__ seg, int* __restrict__ sstart)
{
    int idx = blockIdx.x * 256 + threadIdx.x;
    int b = idx >> 11, t = idx & (T_ - 1);
    const int* sb = seg + b * T_;
    int target = sb[t];
    int lo = 0, hi = t;
    while (lo < hi) { int mid = (lo + hi) >> 1; if (sb[mid] < target) lo = mid + 1; else hi = mid; }
    sstart[idx] = lo;
}

// ---------------- main attention kernel ----------------
__global__ __launch_bounds__(256, 5)
void attn_fwd(const float* __restrict__ qg,
              const int* __restrict__ sstart,
              const unsigned short* __restrict__ ws,
              float* __restrict__ outg)
{
    __shared__ unsigned short sA[TILE_US];
    __shared__ unsigned short sB[TILE_US];   // total 32768 B -> 5 blocks/CU

    const int tid  = threadIdx.x;
    const int wave = tid >> 6;
    const int lane = tid & 63;
    const int qd   = lane >> 4;
    const int ln   = lane & 15;

    const int t0   = ((int)gridDim.x - 1 - (int)blockIdx.x) * 64;  // heavy-first
    const int head = blockIdx.y;
    const int kvh  = head >> 2;
    const int b    = blockIdx.z;

    // ---- preload Q fragments, scaled by log2(e), fp16 hi/lo split ----
    // (B-operand of the swapped QK mfma: same fragment data as before)
    f16x8 qh[4], ql[4];
    {
        const float* qrow =
            qg + (((size_t)(b * T_ + (t0 + wave * 16 + ln)) * NQ_) + head) * D_;
        #pragma unroll
        for (int c = 0; c < 4; ++c) {
            float4 a  = *(const float4*)(qrow + c * 32 + qd * 8);
            float4 b2 = *(const float4*)(qrow + c * 32 + qd * 8 + 4);
            float xs[8] = {a.x, a.y, a.z, a.w, b2.x, b2.y, b2.z, b2.w};
            H8 hu, lu;
            #pragma unroll
            for (int j = 0; j < 8; ++j) {
                float x = xs[j] * LOG2E;
                _Float16 h = (_Float16)x;
                hu.h[j] = h;
                lu.h[j] = (_Float16)(x - (float)h);
            }
            qh[c] = hu.v; ql[c] = lu.v;
        }
    }

    // ---- per-lane row info (this lane's q-row is ln within the wave) ----
    const int trow_l = t0 + wave * 16 + ln;
    const int rs_l   = sstart[b * T_ + trow_l];
    int wave_rs_max = rs_l;
    wave_rs_max = max(wave_rs_max, __shfl_xor(wave_rs_max, 1));
    wave_rs_max = max(wave_rs_max, __shfl_xor(wave_rs_max, 2));
    wave_rs_max = max(wave_rs_max, __shfl_xor(wave_rs_max, 4));
    wave_rs_max = max(wave_rs_max, __shfl_xor(wave_rs_max, 8));
    const int wave_row_min = t0 + wave * 16;

    const int tile0   = sstart[b * T_ + t0] >> 5;       // block-uniform
    const int n_tiles = t0 / 32 + 2;

    f32x4 O[8];
    #pragma unroll
    for (int i = 0; i < 8; ++i) O[i] = (f32x4){0.f, 0.f, 0.f, 0.f};
    float l_lane = 0.f;          // softmax denom for q-row = ln (partial over this qd's kv slots)

    const unsigned short* wsbase =
        ws + ((size_t)((b * NKV_ + kvh) * (T_ / 32))) * TILE_US;

    int koff[4];
    #pragma unroll
    for (int c = 0; c < 4; ++c)
        koff[c] = (ln * 16 + ((4 * c + qd) ^ (ln & 7))) * 8;
    const int vbase = (ln * 4 + (qd ^ ((ln >> 1) & 3))) * 8;

#define STAGE(dst, tl) do {                                                    \
        const unsigned short* _tb = wsbase + (size_t)(tl) * TILE_US;           \
        _Pragma("unroll")                                                      \
        for (int _i = 0; _i < 4; ++_i)                                         \
            dma16(_tb + ((wave * 4 + _i) * 64 + lane) * 8,                     \
                  (dst) + (wave * 4 + _i) * 512);                              \
    } while (0)

    // Swapped QK: S = mfma(Kfrag, Qfrag) -> lane(qd,ln) holds
    // S[kv = s0 + qd*4 + r (+16 for S1)][q-row = ln].  P transpose to the PV
    // A-operand layout (pa[k=qd*8+j] for q-row=ln) is 4 cvt_pk + 4 permlane swaps:
    //   (w0,w2) -> permlane32_swap -> permlane16_swap  gives pa words 0 and 2
    //   (w1,w3) -> same                                gives pa words 1 and 3
#define COMPUTE(BUF, TL) do {                                                  \
        const unsigned short* _Kf = (BUF);                                     \
        const unsigned short* _Vt = (BUF) + 4096;                              \
        const int _s0 = (TL) * 32;                                             \
        f32x4 S0 = {0.f,0.f,0.f,0.f}, S1 = {0.f,0.f,0.f,0.f};                  \
        __builtin_amdgcn_s_setprio(1);                                         \
        _Pragma("unroll")                                                      \
        for (int c = 0; c < 4; ++c) {                                          \
            f16x8 k0 = *(const f16x8*)(_Kf + koff[c]);                         \
            f16x8 k1 = *(const f16x8*)(_Kf + koff[c] + 2048);                  \
            S0 = __builtin_amdgcn_mfma_f32_16x16x32_f16(k0, qh[c], S0,0,0,0);  \
            S1 = __builtin_amdgcn_mfma_f32_16x16x32_f16(k1, qh[c], S1,0,0,0);  \
            S0 = __builtin_amdgcn_mfma_f32_16x16x32_f16(k0, ql[c], S0,0,0,0);  \
            S1 = __builtin_amdgcn_mfma_f32_16x16x32_f16(k1, ql[c], S1,0,0,0);  \
        }                                                                      \
        __builtin_amdgcn_s_setprio(0);                                         \
        bf16x8 bv[8];                                                          \
        _Pragma("unroll")                                                      \
        for (int sub = 0; sub < 8; ++sub)                                      \
            bv[sub] = *(const bf16x8*)(_Vt + vbase + sub * 512);               \
        float p0[4], p1[4];                                                    \
        if (_s0 >= wave_rs_max && _s0 + 31 <= wave_row_min) {                  \
            _Pragma("unroll")                                                  \
            for (int r = 0; r < 4; ++r) {                                      \
                p0[r] = exp2f(S0[r]);                                          \
                p1[r] = exp2f(S1[r]);                                          \
            }                                                                  \
        } else {                                                               \
            _Pragma("unroll")                                                  \
            for (int r = 0; r < 4; ++r) {                                      \
                int kv0 = _s0 + qd * 4 + r;                                    \
                int kv1 = kv0 + 16;                                            \
                float sv0 = (kv0 >= rs_l && kv0 <= trow_l) ? S0[r] : MASKV;    \
                float sv1 = (kv1 >= rs_l && kv1 <= trow_l) ? S1[r] : MASKV;    \
                p0[r] = exp2f(sv0);                                            \
                p1[r] = exp2f(sv1);                                            \
            }                                                                  \
        }                                                                      \
        l_lane += (p0[0] + p0[1]) + (p0[2] + p0[3])                            \
                + (p1[0] + p1[1]) + (p1[2] + p1[3]);                           \
        PKW c0, c1, c2, c3;                                                    \
        c0.h = (bf16x2){(__bf16)p0[0], (__bf16)p0[1]};                         \
        c1.h = (bf16x2){(__bf16)p0[2], (__bf16)p0[3]};                         \
        c2.h = (bf16x2){(__bf16)p1[0], (__bf16)p1[1]};                         \
        c3.h = (bf16x2){(__bf16)p1[2], (__bf16)p1[3]};                         \
        unsigned int w0 = c0.u, w1 = c1.u, w2 = c2.u, w3 = c3.u;               \
        pl32swap(w0, w2); pl32swap(w1, w3);                                    \
        pl16swap(w0, w2); pl16swap(w1, w3);                                    \
        PA4 pw; pw.u[0] = w0; pw.u[1] = w1; pw.u[2] = w2; pw.u[3] = w3;        \
        bf16x8 pa = pw.v;                                                      \
        __builtin_amdgcn_s_setprio(1);                                         \
        _Pragma("unroll")                                                      \
        for (int sub = 0; sub < 8; ++sub)                                      \
            O[sub] = __builtin_amdgcn_mfma_f32_16x16x32_bf16(pa, bv[sub], O[sub],0,0,0); \
        __builtin_amdgcn_s_setprio(0);                                         \
    } while (0)

    int t = tile0;
    STAGE(sA, t);
    __syncthreads();                       // drains DMA into sA
    while (t + 1 < n_tiles) {
        STAGE(sB, t + 1);                  // prefetch under compute(sA)
        COMPUTE(sA, t);
        __syncthreads();                   // drains DMA(sB); sA reads done
        if (t + 2 < n_tiles) STAGE(sA, t + 2);
        COMPUTE(sB, t + 1);
        __syncthreads();                   // drains DMA(sA); sB reads done
        t += 2;
    }
    if (t < n_tiles) COMPUTE(sA, t);

#undef STAGE
#undef COMPUTE

    // ---- epilogue: reduce l across qd groups, transpose via shfl, store ----
    float l = l_lane;
    l += __shfl_xor(l, 16);
    l += __shfl_xor(l, 32);
    const float invl = 1.0f / l;           // per lane: denom for q-row = ln
    int trow[4];
    float inv[4];
    #pragma unroll
    for (int r = 0; r < 4; ++r) {
        trow[r] = t0 + wave * 16 + qd * 4 + r;
        inv[r]  = __shfl(invl, qd * 4 + r);   // lane (qd*4+r) holds denom for that row
    }
    #pragma unroll
    for (int sub = 0; sub < 8; ++sub) {
        #pragma unroll
        for (int r = 0; r < 4; ++r) {
            outg[(((size_t)(b * T_ + trow[r]) * NQ_) + head) * D_ + sub * 16 + ln] =
                O[sub][r] * inv[r];
        }
    }
}

// ---------------- fallback (no-ws path) ----------------
#define KSTR 136
#define VSTR 40
#define PSTR 40
static __device__ __forceinline__ float bf2f(unsigned short h) {
    union { unsigned int u; float f; } c; c.u = (unsigned int)h << 16; return c.f;
}
__global__ __launch_bounds__(256)
void attn_fwd_fb(const float* __restrict__ qg,
                 const float* __restrict__ kg,
                 const float* __restrict__ vg,
                 const int* __restrict__ seg,
                 float* __restrict__ outg)
{
    __shared__ unsigned short sKh[32 * KSTR];
    __shared__ unsigned short sKl[32 * KSTR];
    __shared__ unsigned short sVt[128 * VSTR];
    __shared__ unsigned short sP[4][16 * PSTR];

    const int tid  = threadIdx.x;
    const int wave = tid >> 6;
    const int lane = tid & 63;
    const int qd   = lane >> 4;
    const int ln   = lane & 15;
    const int t0   = ((int)gridDim.x - 1 - (int)blockIdx.x) * 64;
    const int head = blockIdx.y;
    const int kvh  = head >> 2;
    const int b    = blockIdx.z;

    bf16x8 qh[4], ql[4];
    {
        const float* qrow =
            qg + (((size_t)(b * T_ + (t0 + wave * 16 + ln)) * NQ_) + head) * D_;
        #pragma unroll
        for (int c = 0; c < 4; ++c) {
            float4 a  = *(const float4*)(qrow + c * 32 + qd * 8);
            float4 b2 = *(const float4*)(qrow + c * 32 + qd * 8 + 4);
            float xs[8] = {a.x, a.y, a.z, a.w, b2.x, b2.y, b2.z, b2.w};
            U8 hu, lu;
            #pragma unroll
            for (int j = 0; j < 8; ++j) {
                unsigned short h = f2bf(xs[j]);
                hu.us[j] = h;
                lu.us[j] = f2bf(xs[j] - bf2f(h));
            }
            qh[c] = hu.v; ql[c] = lu.v;
        }
    }
    const int* sb = seg + (size_t)b * T_;
    int qseg[4];
    #pragma unroll
    for (int r = 0; r < 4; ++r) qseg[r] = sb[t0 + wave * 16 + qd * 4 + r];
    int tile0;
    {
        int target = sb[t0];
        int lo = 0, hi = t0;
        while (lo < hi) { int mid = (lo + hi) >> 1; if (sb[mid] < target) lo = mid + 1; else hi = mid; }
        tile0 = lo >> 5;
    }
    f32x4 O[8];
    #pragma unroll
    for (int i = 0; i < 8; ++i) O[i] = (f32x4){0.f, 0.f, 0.f, 0.f};
    float m_prev[4], l_lane[4];
    #pragma unroll
    for (int r = 0; r < 4; ++r) { m_prev[r] = MASKV; l_lane[r] = 0.f; }
    const int n_tiles = t0 / 32 + 2;

    for (int tile = tile0; tile < n_tiles; ++tile) {
        const int s0 = tile * 32;
        __syncthreads();
        #pragma unroll
        for (int it = 0; it < 2; ++it) {
            int task = tid + it * 256;
            int r = task >> 4, d = (task & 15) * 8;
            const float* kp = kg + (((size_t)(b * T_ + s0 + r) * NKV_) + kvh) * D_ + d;
            float4 a  = *(const float4*)(kp);
            float4 b2 = *(const float4*)(kp + 4);
            float xs[8] = {a.x, a.y, a.z, a.w, b2.x, b2.y, b2.z, b2.w};
            U8 hu, lu;
            #pragma unroll
            for (int j = 0; j < 8; ++j) {
                unsigned short h = f2bf(xs[j]);
                hu.us[j] = h;
                lu.us[j] = f2bf(xs[j] - bf2f(h));
            }
            *(bf16x8*)(sKh + r * KSTR + d) = hu.v;
            *(bf16x8*)(sKl + r * KSTR + d) = lu.v;
        }
        #pragma unroll
        for (int it = 0; it < 2; ++it) {
            int task = tid + it * 256;
            int d = task & 127, sg = task >> 7;
            const float* vp = vg + (((size_t)(b * T_ + s0 + sg * 8) * NKV_) + kvh) * D_ + d;
            U8 pk;
            #pragma unroll
            for (int j = 0; j < 8; ++j) pk.us[j] = f2bf(vp[j * (NKV_ * D_)]);
            *(bf16x8*)(sVt + d * VSTR + sg * 8) = pk.v;
        }
        __syncthreads();

        f32x4 S0 = {0.f,0.f,0.f,0.f}, S1 = {0.f,0.f,0.f,0.f};
        #pragma unroll
        for (int c = 0; c < 4; ++c) {
            bf16x8 kh0 = *(const bf16x8*)(sKh + ln * KSTR + c * 32 + qd * 8);
            bf16x8 kh1 = *(const bf16x8*)(sKh + (16 + ln) * KSTR + c * 32 + qd * 8);
            bf16x8 kl0 = *(const bf16x8*)(sKl + ln * KSTR + c * 32 + qd * 8);
            bf16x8 kl1 = *(const bf16x8*)(sKl + (16 + ln) * KSTR + c * 32 + qd * 8);
            S0 = __builtin_amdgcn_mfma_f32_16x16x32_bf16(qh[c], kh0, S0, 0, 0, 0);
            S1 = __builtin_amdgcn_mfma_f32_16x16x32_bf16(qh[c], kh1, S1, 0, 0, 0);
            S0 = __builtin_amdgcn_mfma_f32_16x16x32_bf16(qh[c], kl0, S0, 0, 0, 0);
            S1 = __builtin_amdgcn_mfma_f32_16x16x32_bf16(qh[c], kl1, S1, 0, 0, 0);
            S0 = __builtin_amdgcn_mfma_f32_16x16x32_bf16(ql[c], kh0, S0, 0, 0, 0);
            S1 = __builtin_amdgcn_mfma_f32_16x16x32_bf16(ql[c], kh1, S1, 0, 0, 0);
        }
        const int ks0 = sb[s0 + ln];
        const int ks1 = sb[s0 + 16 + ln];
        float p0[4], p1[4], alpha[4];
        #pragma unroll
        for (int r = 0; r < 4; ++r) {
            const int trow = t0 + wave * 16 + qd * 4 + r;
            float s0v = ((s0 + ln <= trow) && (ks0 == qseg[r])) ? S0[r] : MASKV;
            float s1v = ((s0 + 16 + ln <= trow) && (ks1 == qseg[r])) ? S1[r] : MASKV;
            float mx = fmaxf(s0v, s1v);
            mx = fmaxf(mx, __shfl_xor(mx, 1));
            mx = fmaxf(mx, __shfl_xor(mx, 2));
            mx = fmaxf(mx, __shfl_xor(mx, 4));
            mx = fmaxf(mx, __shfl_xor(mx, 8));
            const float mn = fmaxf(m_prev[r], mx);
            alpha[r] = __expf(m_prev[r] - mn);
            p0[r] = __expf(s0v - mn);
            p1[r] = __expf(s1v - mn);
            l_lane[r] = alpha[r] * l_lane[r] + p0[r] + p1[r];
            m_prev[r] = mn;
        }
        #pragma unroll
        for (int i = 0; i < 8; ++i) {
            O[i][0] *= alpha[0]; O[i][1] *= alpha[1];
            O[i][2] *= alpha[2]; O[i][3] *= alpha[3];
        }
        {
            unsigned short* pw = sP[wave] + (qd * 4) * PSTR + ln;
            #pragma unroll
            for (int r = 0; r < 4; ++r) {
                pw[r * PSTR]      = f2bf(p0[r]);
                pw[r * PSTR + 16] = f2bf(p1[r]);
            }
        }
        asm volatile("s_waitcnt lgkmcnt(0)" ::: "memory");
        bf16x8 pa = *(const bf16x8*)(sP[wave] + ln * PSTR + qd * 8);
        #pragma unroll
        for (int sub = 0; sub < 8; ++sub) {
            bf16x8 bv = *(const bf16x8*)(sVt + (sub * 16 + ln) * VSTR + qd * 8);
            O[sub] = __builtin_amdgcn_mfma_f32_16x16x32_bf16(pa, bv, O[sub], 0, 0, 0);
        }
    }
    float inv[4];
    #pragma unroll
    for (int r = 0; r < 4; ++r) {
        float l = l_lane[r];
        l += __shfl_xor(l, 1);
        l += __shfl_xor(l, 2);
        l += __shfl_xor(l, 4);
        l += __shfl_xor(l, 8);
        inv[r] = 1.0f / l;
    }
    #pragma unroll
    for (int sub = 0; sub < 8; ++sub) {
        #pragma unroll
        for (int r = 0; r < 4; ++r) {
            const int trow = t0 + wave * 16 + qd * 4 + r;
            outg[(((size_t)(b * T_ + trow) * NQ_) + head) * D_ + sub * 16 + ln] =
                O[sub][r] * inv[r];
        }
    }
}

extern "C" void kernel_launch(void* const* d_in, const int* in_sizes, int n_in,
                              void* d_out, int out_size, void* d_ws, size_t ws_size,
                              hipStream_t stream) {
    const float* q  = (const float*)d_in[0];
    const float* k  = (const float*)d_in[1];
    const float* v  = (const float*)d_in[2];
    const int*   sg = (const int*)d_in[3];
    float*       o  = (float*)d_out;
    if (ws_size >= WS_NEED) {
        unsigned short* ws = (unsigned short*)d_ws;
        int* sstart = (int*)((char*)d_ws + WS_TILES_BYTES);
        prep<<<dim3(T_ / 32, NKV_, B_), dim3(256), 0, stream>>>(k, v, ws);
        prep_sstart<<<dim3(B_ * T_ / 256), dim3(256), 0, stream>>>(sg, sstart);
        attn_fwd<<<dim3(T_ / 64, NQ_, B_), dim3(256), 0, stream>>>(q, sstart, ws, o);
    } else {
        attn_fwd_fb<<<dim3(T_ / 64, NQ_, B_), dim3(256), 0, stream>>>(q, k, v, sg, o);
    }
}

// Round 2
// 213.261 us; speedup vs baseline: 2.0632x; 2.0632x over previous
//
#include <hip/hip_runtime.h>

// GQA causal+segment-masked flash attention. fp32 in/out.
// B=2, T=2048, NQ=32 (8 kv heads x 4), D=128.
// R9: R8 structure (swapped QK mfma(K,Q); in-register P transpose via
// cvt_pk_bf16 + permlane16/32_swap; no sP LDS -> 32KB; fixed V swizzle
// sc^((d>>1)&3); setprio around MFMA) but WITHOUT the launch_bounds
// min-occupancy forcing that capped VGPR at 48 and caused 506MB of
// scratch spill traffic (R8: 327us). Plain __launch_bounds__(256) as in
// the proven 88-VGPR R7 build.

typedef __bf16 bf16x8 __attribute__((ext_vector_type(8)));
typedef __bf16 bf16x2 __attribute__((ext_vector_type(2)));
typedef _Float16 f16x8 __attribute__((ext_vector_type(8)));
typedef float f32x4 __attribute__((ext_vector_type(4)));
typedef unsigned int uint2v __attribute__((ext_vector_type(2)));

#define B_   2
#define T_   2048
#define NQ_  32
#define NKV_ 8
#define D_   128

#define MASKV (-3.0e38f)
#define LOG2E 1.44269504f
#define TILE_US 8192           // ushorts per 32-col KV tile in ws: 8KB fp16 K + 8KB bf16 Vt
#define WS_TILES_BYTES ((size_t)B_ * NKV_ * (T_ / 32) * TILE_US * 2)   // 16777216
#define WS_NEED (WS_TILES_BYTES + (size_t)B_ * T_ * 4)

static __device__ __forceinline__ unsigned short f2bf(float x) {
    union { float f; unsigned int u; } c; c.f = x;
    unsigned int r = c.u + 0x7fffu + ((c.u >> 16) & 1u);
    return (unsigned short)(r >> 16);
}

union U8  { unsigned short us[8]; bf16x8 v; };
union H8  { _Float16 h[8]; f16x8 v; };
union PKW { bf16x2 h; unsigned int u; };
union PA4 { unsigned int u[4]; bf16x8 v; };

static __device__ __forceinline__ void dma16(const unsigned short* g, unsigned short* l) {
    __builtin_amdgcn_global_load_lds(
        (const __attribute__((address_space(1))) unsigned int*)g,
        (__attribute__((address_space(3))) unsigned int*)l, 16, 0, 0);
}

// register-pair lane swaps (gfx950): a[32:63] <-> b[0:31]  /  a[16:31]<->b[0:15], a[48:63]<->b[32:47]
static __device__ __forceinline__ void pl32swap(unsigned int& a, unsigned int& b) {
#if __has_builtin(__builtin_amdgcn_permlane32_swap)
    uint2v t = __builtin_amdgcn_permlane32_swap(a, b, false, false);
    a = t.x; b = t.y;
#else
    asm("s_nop 1\n\tv_permlane32_swap_b32 %0, %1" : "+v"(a), "+v"(b));
#endif
}
static __device__ __forceinline__ void pl16swap(unsigned int& a, unsigned int& b) {
#if __has_builtin(__builtin_amdgcn_permlane16_swap)
    uint2v t = __builtin_amdgcn_permlane16_swap(a, b, false, false);
    a = t.x; b = t.y;
#else
    asm("s_nop 1\n\tv_permlane16_swap_b32 %0, %1" : "+v"(a), "+v"(b));
#endif
}

// ---------------- prep 1: K -> fp16, V^T -> bf16, swizzled ws tiles ----------------
__global__ __launch_bounds__(256)
void prep(const float* __restrict__ kg, const float* __restrict__ vg,
          unsigned short* __restrict__ ws)
{
    const int tid = threadIdx.x;
    const int st  = blockIdx.x;    // 32-col KV tile index
    const int kvh = blockIdx.y;
    const int b   = blockIdx.z;
    unsigned short* base = ws + ((size_t)((b * NKV_ + kvh) * (T_ / 32) + st)) * TILE_US;

    // K: 512 tasks = 32 rows x 16 chunks(8 elems), fp16
    #pragma unroll
    for (int it = 0; it < 2; ++it) {
        int task = tid + it * 256;
        int r = task >> 4, c = task & 15;
        const float* kp = kg + (((size_t)(b * T_ + st * 32 + r)) * NKV_ + kvh) * D_ + c * 8;
        H8 hu;
        #pragma unroll
        for (int j = 0; j < 8; ++j) hu.h[j] = (_Float16)kp[j];
        int slot = r * 16 + (c ^ (r & 7));
        *(f16x8*)(base + slot * 8) = hu.v;
    }
    // V^T: 512 tasks = 128 d x 4 s-chunks(8 s), bf16
    // swizzle sc ^ ((d>>1)&3): 8 consecutive lanes (d) hit 8 distinct 16B slots
    #pragma unroll
    for (int it = 0; it < 2; ++it) {
        int task = tid + it * 256;
        int d = task & 127, sc = task >> 7;
        const float* vp = vg + (((size_t)(b * T_ + st * 32 + sc * 8)) * NKV_ + kvh) * D_ + d;
        U8 pk;
        #pragma unroll
        for (int j = 0; j < 8; ++j) pk.us[j] = f2bf(vp[j * (NKV_ * D_)]);
        int slot = d * 4 + (sc ^ ((d >> 1) & 3));
        *(bf16x8*)(base + 4096 + slot * 8) = pk.v;
    }
}

// ---------------- prep 2: per-row segment start indices ----------------
__global__ __launch_bounds__(256)
void prep_sstart(const int* __restrict__ seg, int* __restrict__ sstart)
{
    int idx = blockIdx.x * 256 + threadIdx.x;
    int b = idx >> 11, t = idx & (T_ - 1);
    const int* sb = seg + b * T_;
    int target = sb[t];
    int lo = 0, hi = t;
    while (lo < hi) { int mid = (lo + hi) >> 1; if (sb[mid] < target) lo = mid + 1; else hi = mid; }
    sstart[idx] = lo;
}

// ---------------- main attention kernel ----------------
__global__ __launch_bounds__(256)
void attn_fwd(const float* __restrict__ qg,
              const int* __restrict__ sstart,
              const unsigned short* __restrict__ ws,
              float* __restrict__ outg)
{
    __shared__ unsigned short sA[TILE_US];
    __shared__ unsigned short sB[TILE_US];   // total 32768 B

    const int tid  = threadIdx.x;
    const int wave = tid >> 6;
    const int lane = tid & 63;
    const int qd   = lane >> 4;
    const int ln   = lane & 15;

    const int t0   = ((int)gridDim.x - 1 - (int)blockIdx.x) * 64;  // heavy-first
    const int head = blockIdx.y;
    const int kvh  = head >> 2;
    const int b    = blockIdx.z;

    // ---- preload Q fragments, scaled by log2(e), fp16 hi/lo split ----
    // (B-operand of the swapped QK mfma: same fragment data as before)
    f16x8 qh[4], ql[4];
    {
        const float* qrow =
            qg + (((size_t)(b * T_ + (t0 + wave * 16 + ln)) * NQ_) + head) * D_;
        #pragma unroll
        for (int c = 0; c < 4; ++c) {
            float4 a  = *(const float4*)(qrow + c * 32 + qd * 8);
            float4 b2 = *(const float4*)(qrow + c * 32 + qd * 8 + 4);
            float xs[8] = {a.x, a.y, a.z, a.w, b2.x, b2.y, b2.z, b2.w};
            H8 hu, lu;
            #pragma unroll
            for (int j = 0; j < 8; ++j) {
                float x = xs[j] * LOG2E;
                _Float16 h = (_Float16)x;
                hu.h[j] = h;
                lu.h[j] = (_Float16)(x - (float)h);
            }
            qh[c] = hu.v; ql[c] = lu.v;
        }
    }

    // ---- per-lane row info (this lane's q-row is ln within the wave) ----
    const int trow_l = t0 + wave * 16 + ln;
    const int rs_l   = sstart[b * T_ + trow_l];
    int wave_rs_max = rs_l;
    wave_rs_max = max(wave_rs_max, __shfl_xor(wave_rs_max, 1));
    wave_rs_max = max(wave_rs_max, __shfl_xor(wave_rs_max, 2));
    wave_rs_max = max(wave_rs_max, __shfl_xor(wave_rs_max, 4));
    wave_rs_max = max(wave_rs_max, __shfl_xor(wave_rs_max, 8));
    const int wave_row_min = t0 + wave * 16;

    const int tile0   = sstart[b * T_ + t0] >> 5;       // block-uniform
    const int n_tiles = t0 / 32 + 2;

    f32x4 O[8];
    #pragma unroll
    for (int i = 0; i < 8; ++i) O[i] = (f32x4){0.f, 0.f, 0.f, 0.f};
    float l_lane = 0.f;          // softmax denom for q-row = ln (partial over this qd's kv slots)

    const unsigned short* wsbase =
        ws + ((size_t)((b * NKV_ + kvh) * (T_ / 32))) * TILE_US;

    int koff[4];
    #pragma unroll
    for (int c = 0; c < 4; ++c)
        koff[c] = (ln * 16 + ((4 * c + qd) ^ (ln & 7))) * 8;
    const int vbase = (ln * 4 + (qd ^ ((ln >> 1) & 3))) * 8;

#define STAGE(dst, tl) do {                                                    \
        const unsigned short* _tb = wsbase + (size_t)(tl) * TILE_US;           \
        _Pragma("unroll")                                                      \
        for (int _i = 0; _i < 4; ++_i)                                         \
            dma16(_tb + ((wave * 4 + _i) * 64 + lane) * 8,                     \
                  (dst) + (wave * 4 + _i) * 512);                              \
    } while (0)

    // Swapped QK: S = mfma(Kfrag, Qfrag) -> lane(qd,ln) holds
    // S[kv = s0 + qd*4 + r (+16 for S1)][q-row = ln].  P transpose to the PV
    // A-operand layout (pa[k=qd*8+j] for q-row=ln) is 4 cvt_pk + 4 permlane swaps:
    //   (w0,w2) -> permlane32_swap -> permlane16_swap  gives pa words 0 and 2
    //   (w1,w3) -> same                                gives pa words 1 and 3
#define COMPUTE(BUF, TL) do {                                                  \
        const unsigned short* _Kf = (BUF);                                     \
        const unsigned short* _Vt = (BUF) + 4096;                              \
        const int _s0 = (TL) * 32;                                             \
        f32x4 S0 = {0.f,0.f,0.f,0.f}, S1 = {0.f,0.f,0.f,0.f};                  \
        __builtin_amdgcn_s_setprio(1);                                         \
        _Pragma("unroll")                                                      \
        for (int c = 0; c < 4; ++c) {                                          \
            f16x8 k0 = *(const f16x8*)(_Kf + koff[c]);                         \
            f16x8 k1 = *(const f16x8*)(_Kf + koff[c] + 2048);                  \
            S0 = __builtin_amdgcn_mfma_f32_16x16x32_f16(k0, qh[c], S0,0,0,0);  \
            S1 = __builtin_amdgcn_mfma_f32_16x16x32_f16(k1, qh[c], S1,0,0,0);  \
            S0 = __builtin_amdgcn_mfma_f32_16x16x32_f16(k0, ql[c], S0,0,0,0);  \
            S1 = __builtin_amdgcn_mfma_f32_16x16x32_f16(k1, ql[c], S1,0,0,0);  \
        }                                                                      \
        __builtin_amdgcn_s_setprio(0);                                         \
        bf16x8 bv[8];                                                          \
        _Pragma("unroll")                                                      \
        for (int sub = 0; sub < 8; ++sub)                                      \
            bv[sub] = *(const bf16x8*)(_Vt + vbase + sub * 512);               \
        float p0[4], p1[4];                                                    \
        if (_s0 >= wave_rs_max && _s0 + 31 <= wave_row_min) {                  \
            _Pragma("unroll")                                                  \
            for (int r = 0; r < 4; ++r) {                                      \
                p0[r] = exp2f(S0[r]);                                          \
                p1[r] = exp2f(S1[r]);                                          \
            }                                                                  \
        } else {                                                               \
            _Pragma("unroll")                                                  \
            for (int r = 0; r < 4; ++r) {                                      \
                int kv0 = _s0 + qd * 4 + r;                                    \
                int kv1 = kv0 + 16;                                            \
                float sv0 = (kv0 >= rs_l && kv0 <= trow_l) ? S0[r] : MASKV;    \
                float sv1 = (kv1 >= rs_l && kv1 <= trow_l) ? S1[r] : MASKV;    \
                p0[r] = exp2f(sv0);                                            \
                p1[r] = exp2f(sv1);                                            \
            }                                                                  \
        }                                                                      \
        l_lane += (p0[0] + p0[1]) + (p0[2] + p0[3])                            \
                + (p1[0] + p1[1]) + (p1[2] + p1[3]);                           \
        PKW c0, c1, c2, c3;                                                    \
        c0.h = (bf16x2){(__bf16)p0[0], (__bf16)p0[1]};                         \
        c1.h = (bf16x2){(__bf16)p0[2], (__bf16)p0[3]};                         \
        c2.h = (bf16x2){(__bf16)p1[0], (__bf16)p1[1]};                         \
        c3.h = (bf16x2){(__bf16)p1[2], (__bf16)p1[3]};                         \
        unsigned int w0 = c0.u, w1 = c1.u, w2 = c2.u, w3 = c3.u;               \
        pl32swap(w0, w2); pl32swap(w1, w3);                                    \
        pl16swap(w0, w2); pl16swap(w1, w3);                                    \
        PA4 pw; pw.u[0] = w0; pw.u[1] = w1; pw.u[2] = w2; pw.u[3] = w3;        \
        bf16x8 pa = pw.v;                                                      \
        __builtin_amdgcn_s_setprio(1);                                         \
        _Pragma("unroll")                                                      \
        for (int sub = 0; sub < 8; ++sub)                                      \
            O[sub] = __builtin_amdgcn_mfma_f32_16x16x32_bf16(pa, bv[sub], O[sub],0,0,0); \
        __builtin_amdgcn_s_setprio(0);                                         \
    } while (0)

    int t = tile0;
    STAGE(sA, t);
    __syncthreads();                       // drains DMA into sA
    while (t + 1 < n_tiles) {
        STAGE(sB, t + 1);                  // prefetch under compute(sA)
        COMPUTE(sA, t);
        __syncthreads();                   // drains DMA(sB); sA reads done
        if (t + 2 < n_tiles) STAGE(sA, t + 2);
        COMPUTE(sB, t + 1);
        __syncthreads();                   // drains DMA(sA); sB reads done
        t += 2;
    }
    if (t < n_tiles) COMPUTE(sA, t);

#undef STAGE
#undef COMPUTE

    // ---- epilogue: reduce l across qd groups, redistribute via shfl, store ----
    float l = l_lane;
    l += __shfl_xor(l, 16);
    l += __shfl_xor(l, 32);
    const float invl = 1.0f / l;           // per lane: denom for q-row = ln
    int trow[4];
    float inv[4];
    #pragma unroll
    for (int r = 0; r < 4; ++r) {
        trow[r] = t0 + wave * 16 + qd * 4 + r;
        inv[r]  = __shfl(invl, qd * 4 + r);   // lane (qd*4+r) holds denom for that row
    }
    #pragma unroll
    for (int sub = 0; sub < 8; ++sub) {
        #pragma unroll
        for (int r = 0; r < 4; ++r) {
            outg[(((size_t)(b * T_ + trow[r]) * NQ_) + head) * D_ + sub * 16 + ln] =
                O[sub][r] * inv[r];
        }
    }
}

// ---------------- fallback (no-ws path) ----------------
#define KSTR 136
#define VSTR 40
#define PSTR 40
static __device__ __forceinline__ float bf2f(unsigned short h) {
    union { unsigned int u; float f; } c; c.u = (unsigned int)h << 16; return c.f;
}
__global__ __launch_bounds__(256)
void attn_fwd_fb(const float* __restrict__ qg,
                 const float* __restrict__ kg,
                 const float* __restrict__ vg,
                 const int* __restrict__ seg,
                 float* __restrict__ outg)
{
    __shared__ unsigned short sKh[32 * KSTR];
    __shared__ unsigned short sKl[32 * KSTR];
    __shared__ unsigned short sVt[128 * VSTR];
    __shared__ unsigned short sP[4][16 * PSTR];

    const int tid  = threadIdx.x;
    const int wave = tid >> 6;
    const int lane = tid & 63;
    const int qd   = lane >> 4;
    const int ln   = lane & 15;
    const int t0   = ((int)gridDim.x - 1 - (int)blockIdx.x) * 64;
    const int head = blockIdx.y;
    const int kvh  = head >> 2;
    const int b    = blockIdx.z;

    bf16x8 qh[4], ql[4];
    {
        const float* qrow =
            qg + (((size_t)(b * T_ + (t0 + wave * 16 + ln)) * NQ_) + head) * D_;
        #pragma unroll
        for (int c = 0; c < 4; ++c) {
            float4 a  = *(const float4*)(qrow + c * 32 + qd * 8);
            float4 b2 = *(const float4*)(qrow + c * 32 + qd * 8 + 4);
            float xs[8] = {a.x, a.y, a.z, a.w, b2.x, b2.y, b2.z, b2.w};
            U8 hu, lu;
            #pragma unroll
            for (int j = 0; j < 8; ++j) {
                unsigned short h = f2bf(xs[j]);
                hu.us[j] = h;
                lu.us[j] = f2bf(xs[j] - bf2f(h));
            }
            qh[c] = hu.v; ql[c] = lu.v;
        }
    }
    const int* sb = seg + (size_t)b * T_;
    int qseg[4];
    #pragma unroll
    for (int r = 0; r < 4; ++r) qseg[r] = sb[t0 + wave * 16 + qd * 4 + r];
    int tile0;
    {
        int target = sb[t0];
        int lo = 0, hi = t0;
        while (lo < hi) { int mid = (lo + hi) >> 1; if (sb[mid] < target) lo = mid + 1; else hi = mid; }
        tile0 = lo >> 5;
    }
    f32x4 O[8];
    #pragma unroll
    for (int i = 0; i < 8; ++i) O[i] = (f32x4){0.f, 0.f, 0.f, 0.f};
    float m_prev[4], l_lane[4];
    #pragma unroll
    for (int r = 0; r < 4; ++r) { m_prev[r] = MASKV; l_lane[r] = 0.f; }
    const int n_tiles = t0 / 32 + 2;

    for (int tile = tile0; tile < n_tiles; ++tile) {
        const int s0 = tile * 32;
        __syncthreads();
        #pragma unroll
        for (int it = 0; it < 2; ++it) {
            int task = tid + it * 256;
            int r = task >> 4, d = (task & 15) * 8;
            const float* kp = kg + (((size_t)(b * T_ + s0 + r) * NKV_) + kvh) * D_ + d;
            float4 a  = *(const float4*)(kp);
            float4 b2 = *(const float4*)(kp + 4);
            float xs[8] = {a.x, a.y, a.z, a.w, b2.x, b2.y, b2.z, b2.w};
            U8 hu, lu;
            #pragma unroll
            for (int j = 0; j < 8; ++j) {
                unsigned short h = f2bf(xs[j]);
                hu.us[j] = h;
                lu.us[j] = f2bf(xs[j] - bf2f(h));
            }
            *(bf16x8*)(sKh + r * KSTR + d) = hu.v;
            *(bf16x8*)(sKl + r * KSTR + d) = lu.v;
        }
        #pragma unroll
        for (int it = 0; it < 2; ++it) {
            int task = tid + it * 256;
            int d = task & 127, sg = task >> 7;
            const float* vp = vg + (((size_t)(b * T_ + s0 + sg * 8) * NKV_) + kvh) * D_ + d;
            U8 pk;
            #pragma unroll
            for (int j = 0; j < 8; ++j) pk.us[j] = f2bf(vp[j * (NKV_ * D_)]);
            *(bf16x8*)(sVt + d * VSTR + sg * 8) = pk.v;
        }
        __syncthreads();

        f32x4 S0 = {0.f,0.f,0.f,0.f}, S1 = {0.f,0.f,0.f,0.f};
        #pragma unroll
        for (int c = 0; c < 4; ++c) {
            bf16x8 kh0 = *(const bf16x8*)(sKh + ln * KSTR + c * 32 + qd * 8);
            bf16x8 kh1 = *(const bf16x8*)(sKh + (16 + ln) * KSTR + c * 32 + qd * 8);
            bf16x8 kl0 = *(const bf16x8*)(sKl + ln * KSTR + c * 32 + qd * 8);
            bf16x8 kl1 = *(const bf16x8*)(sKl + (16 + ln) * KSTR + c * 32 + qd * 8);
            S0 = __builtin_amdgcn_mfma_f32_16x16x32_bf16(qh[c], kh0, S0, 0, 0, 0);
            S1 = __builtin_amdgcn_mfma_f32_16x16x32_bf16(qh[c], kh1, S1, 0, 0, 0);
            S0 = __builtin_amdgcn_mfma_f32_16x16x32_bf16(qh[c], kl0, S0, 0, 0, 0);
            S1 = __builtin_amdgcn_mfma_f32_16x16x32_bf16(qh[c], kl1, S1, 0, 0, 0);
            S0 = __builtin_amdgcn_mfma_f32_16x16x32_bf16(ql[c], kh0, S0, 0, 0, 0);
            S1 = __builtin_amdgcn_mfma_f32_16x16x32_bf16(ql[c], kh1, S1, 0, 0, 0);
        }
        const int ks0 = sb[s0 + ln];
        const int ks1 = sb[s0 + 16 + ln];
        float p0[4], p1[4], alpha[4];
        #pragma unroll
        for (int r = 0; r < 4; ++r) {
            const int trow = t0 + wave * 16 + qd * 4 + r;
            float s0v = ((s0 + ln <= trow) && (ks0 == qseg[r])) ? S0[r] : MASKV;
            float s1v = ((s0 + 16 + ln <= trow) && (ks1 == qseg[r])) ? S1[r] : MASKV;
            float mx = fmaxf(s0v, s1v);
            mx = fmaxf(mx, __shfl_xor(mx, 1));
            mx = fmaxf(mx, __shfl_xor(mx, 2));
            mx = fmaxf(mx, __shfl_xor(mx, 4));
            mx = fmaxf(mx, __shfl_xor(mx, 8));
            const float mn = fmaxf(m_prev[r], mx);
            alpha[r] = __expf(m_prev[r] - mn);
            p0[r] = __expf(s0v - mn);
            p1[r] = __expf(s1v - mn);
            l_lane[r] = alpha[r] * l_lane[r] + p0[r] + p1[r];
            m_prev[r] = mn;
        }
        #pragma unroll
        for (int i = 0; i < 8; ++i) {
            O[i][0] *= alpha[0]; O[i][1] *= alpha[1];
            O[i][2] *= alpha[2]; O[i][3] *= alpha[3];
        }
        {
            unsigned short* pw = sP[wave] + (qd * 4) * PSTR + ln;
            #pragma unroll
            for (int r = 0; r < 4; ++r) {
                pw[r * PSTR]      = f2bf(p0[r]);
                pw[r * PSTR + 16] = f2bf(p1[r]);
            }
        }
        asm volatile("s_waitcnt lgkmcnt(0)" ::: "memory");
        bf16x8 pa = *(const bf16x8*)(sP[wave] + ln * PSTR + qd * 8);
        #pragma unroll
        for (int sub = 0; sub < 8; ++sub) {
            bf16x8 bv = *(const bf16x8*)(sVt + (sub * 16 + ln) * VSTR + qd * 8);
            O[sub] = __builtin_amdgcn_mfma_f32_16x16x32_bf16(pa, bv, O[sub], 0, 0, 0);
        }
    }
    float inv[4];
    #pragma unroll
    for (int r = 0; r < 4; ++r) {
        float l = l_lane[r];
        l += __shfl_xor(l, 1);
        l += __shfl_xor(l, 2);
        l += __shfl_xor(l, 4);
        l += __shfl_xor(l, 8);
        inv[r] = 1.0f / l;
    }
    #pragma unroll
    for (int sub = 0; sub < 8; ++sub) {
        #pragma unroll
        for (int r = 0; r < 4; ++r) {
            const int trow = t0 + wave * 16 + qd * 4 + r;
            outg[(((size_t)(b * T_ + trow) * NQ_) + head) * D_ + sub * 16 + ln] =
                O[sub][r] * inv[r];
        }
    }
}

extern "C" void kernel_launch(void* const* d_in, const int* in_sizes, int n_in,
                              void* d_out, int out_size, void* d_ws, size_t ws_size,
                              hipStream_t stream) {
    const float* q  = (const float*)d_in[0];
    const float* k  = (const float*)d_in[1];
    const float* v  = (const float*)d_in[2];
    const int*   sg = (const int*)d_in[3];
    float*       o  = (float*)d_out;
    if (ws_size >= WS_NEED) {
        unsigned short* ws = (unsigned short*)d_ws;
        int* sstart = (int*)((char*)d_ws + WS_TILES_BYTES);
        prep<<<dim3(T_ / 32, NKV_, B_), dim3(256), 0, stream>>>(k, v, ws);
        prep_sstart<<<dim3(B_ * T_ / 256), dim3(256), 0, stream>>>(sg, sstart);
        attn_fwd<<<dim3(T_ / 64, NQ_, B_), dim3(256), 0, stream>>>(q, sstart, ws, o);
    } else {
        attn_fwd_fb<<<dim3(T_ / 64, NQ_, B_), dim3(256), 0, stream>>>(q, k, v, sg, o);
    }
}

// Round 3
// 211.035 us; speedup vs baseline: 2.0850x; 1.0105x over previous
//
#include <hip/hip_runtime.h>

// GQA causal+segment-masked flash attention. fp32 in/out.
// B=2, T=2048, NQ=32 (8 kv heads x 4), D=128.
// R10: R9 core (swapped QK mfma(K,Q); in-register P transpose via
// cvt_pk_bf16 + permlane16/32_swap; 32KB LDS; fixed V swizzle; setprio)
// + FOLDED CAUSAL TRIANGLE: each block processes Q-tile pair (31-i, i)
// sequentially -> uniform ~18 tiles/block, grid 1024 blocks = 4/CU fully
// resident (was 2048 skewed blocks, 14% time-avg occupancy, long tail).

typedef __bf16 bf16x8 __attribute__((ext_vector_type(8)));
typedef __bf16 bf16x2 __attribute__((ext_vector_type(2)));
typedef _Float16 f16x8 __attribute__((ext_vector_type(8)));
typedef float f32x4 __attribute__((ext_vector_type(4)));
typedef unsigned int uint2v __attribute__((ext_vector_type(2)));

#define B_   2
#define T_   2048
#define NQ_  32
#define NKV_ 8
#define D_   128

#define MASKV (-3.0e38f)
#define LOG2E 1.44269504f
#define TILE_US 8192           // ushorts per 32-col KV tile in ws: 8KB fp16 K + 8KB bf16 Vt
#define WS_TILES_BYTES ((size_t)B_ * NKV_ * (T_ / 32) * TILE_US * 2)   // 16777216
#define WS_NEED (WS_TILES_BYTES + (size_t)B_ * T_ * 4)

static __device__ __forceinline__ unsigned short f2bf(float x) {
    union { float f; unsigned int u; } c; c.f = x;
    unsigned int r = c.u + 0x7fffu + ((c.u >> 16) & 1u);
    return (unsigned short)(r >> 16);
}

union U8  { unsigned short us[8]; bf16x8 v; };
union H8  { _Float16 h[8]; f16x8 v; };
union PKW { bf16x2 h; unsigned int u; };
union PA4 { unsigned int u[4]; bf16x8 v; };

static __device__ __forceinline__ void dma16(const unsigned short* g, unsigned short* l) {
    __builtin_amdgcn_global_load_lds(
        (const __attribute__((address_space(1))) unsigned int*)g,
        (__attribute__((address_space(3))) unsigned int*)l, 16, 0, 0);
}

// register-pair lane swaps (gfx950): a[32:63] <-> b[0:31]  /  a[16:31]<->b[0:15], a[48:63]<->b[32:47]
static __device__ __forceinline__ void pl32swap(unsigned int& a, unsigned int& b) {
#if __has_builtin(__builtin_amdgcn_permlane32_swap)
    uint2v t = __builtin_amdgcn_permlane32_swap(a, b, false, false);
    a = t.x; b = t.y;
#else
    asm("s_nop 1\n\tv_permlane32_swap_b32 %0, %1" : "+v"(a), "+v"(b));
#endif
}
static __device__ __forceinline__ void pl16swap(unsigned int& a, unsigned int& b) {
#if __has_builtin(__builtin_amdgcn_permlane16_swap)
    uint2v t = __builtin_amdgcn_permlane16_swap(a, b, false, false);
    a = t.x; b = t.y;
#else
    asm("s_nop 1\n\tv_permlane16_swap_b32 %0, %1" : "+v"(a), "+v"(b));
#endif
}

// ---------------- prep 1: K -> fp16, V^T -> bf16, swizzled ws tiles ----------------
__global__ __launch_bounds__(256)
void prep(const float* __restrict__ kg, const float* __restrict__ vg,
          unsigned short* __restrict__ ws)
{
    const int tid = threadIdx.x;
    const int st  = blockIdx.x;    // 32-col KV tile index
    const int kvh = blockIdx.y;
    const int b   = blockIdx.z;
    unsigned short* base = ws + ((size_t)((b * NKV_ + kvh) * (T_ / 32) + st)) * TILE_US;

    // K: 512 tasks = 32 rows x 16 chunks(8 elems), fp16
    #pragma unroll
    for (int it = 0; it < 2; ++it) {
        int task = tid + it * 256;
        int r = task >> 4, c = task & 15;
        const float* kp = kg + (((size_t)(b * T_ + st * 32 + r)) * NKV_ + kvh) * D_ + c * 8;
        H8 hu;
        #pragma unroll
        for (int j = 0; j < 8; ++j) hu.h[j] = (_Float16)kp[j];
        int slot = r * 16 + (c ^ (r & 7));
        *(f16x8*)(base + slot * 8) = hu.v;
    }
    // V^T: 512 tasks = 128 d x 4 s-chunks(8 s), bf16
    // swizzle sc ^ ((d>>1)&3): 8 consecutive lanes (d) hit 8 distinct 16B slots
    #pragma unroll
    for (int it = 0; it < 2; ++it) {
        int task = tid + it * 256;
        int d = task & 127, sc = task >> 7;
        const float* vp = vg + (((size_t)(b * T_ + st * 32 + sc * 8)) * NKV_ + kvh) * D_ + d;
        U8 pk;
        #pragma unroll
        for (int j = 0; j < 8; ++j) pk.us[j] = f2bf(vp[j * (NKV_ * D_)]);
        int slot = d * 4 + (sc ^ ((d >> 1) & 3));
        *(bf16x8*)(base + 4096 + slot * 8) = pk.v;
    }
}

// ---------------- prep 2: per-row segment start indices ----------------
__global__ __launch_bounds__(256)
void prep_sstart(const int* __restrict__ seg, int* __restrict__ sstart)
{
    int idx = blockIdx.x * 256 + threadIdx.x;
    int b = idx >> 11, t = idx & (T_ - 1);
    const int* sb = seg + b * T_;
    int target = sb[t];
    int lo = 0, hi = t;
    while (lo < hi) { int mid = (lo + hi) >> 1; if (sb[mid] < target) lo = mid + 1; else hi = mid; }
    sstart[idx] = lo;
}

// ---------------- main attention kernel ----------------
__global__ __launch_bounds__(256)
void attn_fwd(const float* __restrict__ qg,
              const int* __restrict__ sstart,
              const unsigned short* __restrict__ ws,
              float* __restrict__ outg)
{
    __shared__ unsigned short sA[TILE_US];
    __shared__ unsigned short sB[TILE_US];   // total 32768 B -> 5 blocks/CU capacity

    const int tid  = threadIdx.x;
    const int wave = tid >> 6;
    const int lane = tid & 63;
    const int qd   = lane >> 4;
    const int ln   = lane & 15;

    const int i    = blockIdx.x;             // 0..15 (folded pair index)
    const int head = blockIdx.y;
    const int kvh  = head >> 2;
    const int b    = blockIdx.z;

    const unsigned short* wsbase =
        ws + ((size_t)((b * NKV_ + kvh) * (T_ / 32))) * TILE_US;

    int koff[4];
    #pragma unroll
    for (int c = 0; c < 4; ++c)
        koff[c] = (ln * 16 + ((4 * c + qd) ^ (ln & 7))) * 8;
    const int vbase = (ln * 4 + (qd ^ ((ln >> 1) & 3))) * 8;

#define STAGE(dst, tl) do {                                                    \
        const unsigned short* _tb = wsbase + (size_t)(tl) * TILE_US;           \
        _Pragma("unroll")                                                      \
        for (int _i = 0; _i < 4; ++_i)                                         \
            dma16(_tb + ((wave * 4 + _i) * 64 + lane) * 8,                     \
                  (dst) + (wave * 4 + _i) * 512);                              \
    } while (0)

    // Swapped QK: S = mfma(Kfrag, Qfrag) -> lane(qd,ln) holds
    // S[kv = s0 + qd*4 + r (+16 for S1)][q-row = ln].  P transpose to the PV
    // A-operand layout (pa[k=qd*8+j] for q-row=ln) is 4 cvt_pk + 4 permlane swaps.
#define COMPUTE(BUF, TL) do {                                                  \
        const unsigned short* _Kf = (BUF);                                     \
        const unsigned short* _Vt = (BUF) + 4096;                              \
        const int _s0 = (TL) * 32;                                             \
        f32x4 S0 = {0.f,0.f,0.f,0.f}, S1 = {0.f,0.f,0.f,0.f};                  \
        __builtin_amdgcn_s_setprio(1);                                         \
        _Pragma("unroll")                                                      \
        for (int c = 0; c < 4; ++c) {                                          \
            f16x8 k0 = *(const f16x8*)(_Kf + koff[c]);                         \
            f16x8 k1 = *(const f16x8*)(_Kf + koff[c] + 2048);                  \
            S0 = __builtin_amdgcn_mfma_f32_16x16x32_f16(k0, qh[c], S0,0,0,0);  \
            S1 = __builtin_amdgcn_mfma_f32_16x16x32_f16(k1, qh[c], S1,0,0,0);  \
            S0 = __builtin_amdgcn_mfma_f32_16x16x32_f16(k0, ql[c], S0,0,0,0);  \
            S1 = __builtin_amdgcn_mfma_f32_16x16x32_f16(k1, ql[c], S1,0,0,0);  \
        }                                                                      \
        __builtin_amdgcn_s_setprio(0);                                         \
        bf16x8 bv[8];                                                          \
        _Pragma("unroll")                                                      \
        for (int sub = 0; sub < 8; ++sub)                                      \
            bv[sub] = *(const bf16x8*)(_Vt + vbase + sub * 512);               \
        float p0[4], p1[4];                                                    \
        if (_s0 >= wave_rs_max && _s0 + 31 <= wave_row_min) {                  \
            _Pragma("unroll")                                                  \
            for (int r = 0; r < 4; ++r) {                                      \
                p0[r] = exp2f(S0[r]);                                          \
                p1[r] = exp2f(S1[r]);                                          \
            }                                                                  \
        } else {                                                               \
            _Pragma("unroll")                                                  \
            for (int r = 0; r < 4; ++r) {                                      \
                int kv0 = _s0 + qd * 4 + r;                                    \
                int kv1 = kv0 + 16;                                            \
                float sv0 = (kv0 >= rs_l && kv0 <= trow_l) ? S0[r] : MASKV;    \
                float sv1 = (kv1 >= rs_l && kv1 <= trow_l) ? S1[r] : MASKV;    \
                p0[r] = exp2f(sv0);                                            \
                p1[r] = exp2f(sv1);                                            \
            }                                                                  \
        }                                                                      \
        l_lane += (p0[0] + p0[1]) + (p0[2] + p0[3])                            \
                + (p1[0] + p1[1]) + (p1[2] + p1[3]);                           \
        PKW c0, c1, c2, c3;                                                    \
        c0.h = (bf16x2){(__bf16)p0[0], (__bf16)p0[1]};                         \
        c1.h = (bf16x2){(__bf16)p0[2], (__bf16)p0[3]};                         \
        c2.h = (bf16x2){(__bf16)p1[0], (__bf16)p1[1]};                         \
        c3.h = (bf16x2){(__bf16)p1[2], (__bf16)p1[3]};                         \
        unsigned int w0 = c0.u, w1 = c1.u, w2 = c2.u, w3 = c3.u;               \
        pl32swap(w0, w2); pl32swap(w1, w3);                                    \
        pl16swap(w0, w2); pl16swap(w1, w3);                                    \
        PA4 pw; pw.u[0] = w0; pw.u[1] = w1; pw.u[2] = w2; pw.u[3] = w3;        \
        bf16x8 pa = pw.v;                                                      \
        __builtin_amdgcn_s_setprio(1);                                         \
        _Pragma("unroll")                                                      \
        for (int sub = 0; sub < 8; ++sub)                                      \
            O[sub] = __builtin_amdgcn_mfma_f32_16x16x32_bf16(pa, bv[sub], O[sub],0,0,0); \
        __builtin_amdgcn_s_setprio(0);                                         \
    } while (0)

    // Folded pair: phase 0 = heavy Q-tile (2*gridDim.x-1-i), phase 1 = light (i).
    // Sum of tile counts is ~constant across blocks -> uniform block duration.
    for (int phase = 0; phase < 2; ++phase) {
        const int t0 = (phase == 0 ? (2 * (int)gridDim.x - 1 - i) : i) * 64;

        // ---- preload Q fragments, scaled by log2(e), fp16 hi/lo split ----
        f16x8 qh[4], ql[4];
        {
            const float* qrow =
                qg + (((size_t)(b * T_ + (t0 + wave * 16 + ln)) * NQ_) + head) * D_;
            #pragma unroll
            for (int c = 0; c < 4; ++c) {
                float4 a  = *(const float4*)(qrow + c * 32 + qd * 8);
                float4 b2 = *(const float4*)(qrow + c * 32 + qd * 8 + 4);
                float xs[8] = {a.x, a.y, a.z, a.w, b2.x, b2.y, b2.z, b2.w};
                H8 hu, lu;
                #pragma unroll
                for (int j = 0; j < 8; ++j) {
                    float x = xs[j] * LOG2E;
                    _Float16 h = (_Float16)x;
                    hu.h[j] = h;
                    lu.h[j] = (_Float16)(x - (float)h);
                }
                qh[c] = hu.v; ql[c] = lu.v;
            }
        }

        // ---- per-lane row info (this lane's q-row is ln within the wave) ----
        const int trow_l = t0 + wave * 16 + ln;
        const int rs_l   = sstart[b * T_ + trow_l];
        int wave_rs_max = rs_l;
        wave_rs_max = max(wave_rs_max, __shfl_xor(wave_rs_max, 1));
        wave_rs_max = max(wave_rs_max, __shfl_xor(wave_rs_max, 2));
        wave_rs_max = max(wave_rs_max, __shfl_xor(wave_rs_max, 4));
        wave_rs_max = max(wave_rs_max, __shfl_xor(wave_rs_max, 8));
        const int wave_row_min = t0 + wave * 16;

        const int tile0   = sstart[b * T_ + t0] >> 5;       // block-uniform
        const int n_tiles = t0 / 32 + 2;

        f32x4 O[8];
        #pragma unroll
        for (int k = 0; k < 8; ++k) O[k] = (f32x4){0.f, 0.f, 0.f, 0.f};
        float l_lane = 0.f;      // softmax denom for q-row = ln (partial over this qd's kv slots)

        __syncthreads();         // phase 1: all waves done reading LDS from phase 0

        int t = tile0;
        STAGE(sA, t);
        __syncthreads();                       // drains DMA into sA
        while (t + 1 < n_tiles) {
            STAGE(sB, t + 1);                  // prefetch under compute(sA)
            COMPUTE(sA, t);
            __syncthreads();                   // drains DMA(sB); sA reads done
            if (t + 2 < n_tiles) STAGE(sA, t + 2);
            COMPUTE(sB, t + 1);
            __syncthreads();                   // drains DMA(sA); sB reads done
            t += 2;
        }
        if (t < n_tiles) COMPUTE(sA, t);

        // ---- epilogue: reduce l across qd groups, redistribute via shfl, store ----
        float l = l_lane;
        l += __shfl_xor(l, 16);
        l += __shfl_xor(l, 32);
        const float invl = 1.0f / l;           // per lane: denom for q-row = ln
        int trow[4];
        float inv[4];
        #pragma unroll
        for (int r = 0; r < 4; ++r) {
            trow[r] = t0 + wave * 16 + qd * 4 + r;
            inv[r]  = __shfl(invl, qd * 4 + r);   // lane (qd*4+r) holds denom for that row
        }
        #pragma unroll
        for (int sub = 0; sub < 8; ++sub) {
            #pragma unroll
            for (int r = 0; r < 4; ++r) {
                outg[(((size_t)(b * T_ + trow[r]) * NQ_) + head) * D_ + sub * 16 + ln] =
                    O[sub][r] * inv[r];
            }
        }
    }

#undef STAGE
#undef COMPUTE
}

// ---------------- fallback (no-ws path) ----------------
#define KSTR 136
#define VSTR 40
#define PSTR 40
static __device__ __forceinline__ float bf2f(unsigned short h) {
    union { unsigned int u; float f; } c; c.u = (unsigned int)h << 16; return c.f;
}
__global__ __launch_bounds__(256)
void attn_fwd_fb(const float* __restrict__ qg,
                 const float* __restrict__ kg,
                 const float* __restrict__ vg,
                 const int* __restrict__ seg,
                 float* __restrict__ outg)
{
    __shared__ unsigned short sKh[32 * KSTR];
    __shared__ unsigned short sKl[32 * KSTR];
    __shared__ unsigned short sVt[128 * VSTR];
    __shared__ unsigned short sP[4][16 * PSTR];

    const int tid  = threadIdx.x;
    const int wave = tid >> 6;
    const int lane = tid & 63;
    const int qd   = lane >> 4;
    const int ln   = lane & 15;
    const int t0   = ((int)gridDim.x - 1 - (int)blockIdx.x) * 64;
    const int head = blockIdx.y;
    const int kvh  = head >> 2;
    const int b    = blockIdx.z;

    bf16x8 qh[4], ql[4];
    {
        const float* qrow =
            qg + (((size_t)(b * T_ + (t0 + wave * 16 + ln)) * NQ_) + head) * D_;
        #pragma unroll
        for (int c = 0; c < 4; ++c) {
            float4 a  = *(const float4*)(qrow + c * 32 + qd * 8);
            float4 b2 = *(const float4*)(qrow + c * 32 + qd * 8 + 4);
            float xs[8] = {a.x, a.y, a.z, a.w, b2.x, b2.y, b2.z, b2.w};
            U8 hu, lu;
            #pragma unroll
            for (int j = 0; j < 8; ++j) {
                unsigned short h = f2bf(xs[j]);
                hu.us[j] = h;
                lu.us[j] = f2bf(xs[j] - bf2f(h));
            }
            qh[c] = hu.v; ql[c] = lu.v;
        }
    }
    const int* sb = seg + (size_t)b * T_;
    int qseg[4];
    #pragma unroll
    for (int r = 0; r < 4; ++r) qseg[r] = sb[t0 + wave * 16 + qd * 4 + r];
    int tile0;
    {
        int target = sb[t0];
        int lo = 0, hi = t0;
        while (lo < hi) { int mid = (lo + hi) >> 1; if (sb[mid] < target) lo = mid + 1; else hi = mid; }
        tile0 = lo >> 5;
    }
    f32x4 O[8];
    #pragma unroll
    for (int i = 0; i < 8; ++i) O[i] = (f32x4){0.f, 0.f, 0.f, 0.f};
    float m_prev[4], l_lane[4];
    #pragma unroll
    for (int r = 0; r < 4; ++r) { m_prev[r] = MASKV; l_lane[r] = 0.f; }
    const int n_tiles = t0 / 32 + 2;

    for (int tile = tile0; tile < n_tiles; ++tile) {
        const int s0 = tile * 32;
        __syncthreads();
        #pragma unroll
        for (int it = 0; it < 2; ++it) {
            int task = tid + it * 256;
            int r = task >> 4, d = (task & 15) * 8;
            const float* kp = kg + (((size_t)(b * T_ + s0 + r) * NKV_) + kvh) * D_ + d;
            float4 a  = *(const float4*)(kp);
            float4 b2 = *(const float4*)(kp + 4);
            float xs[8] = {a.x, a.y, a.z, a.w, b2.x, b2.y, b2.z, b2.w};
            U8 hu, lu;
            #pragma unroll
            for (int j = 0; j < 8; ++j) {
                unsigned short h = f2bf(xs[j]);
                hu.us[j] = h;
                lu.us[j] = f2bf(xs[j] - bf2f(h));
            }
            *(bf16x8*)(sKh + r * KSTR + d) = hu.v;
            *(bf16x8*)(sKl + r * KSTR + d) = lu.v;
        }
        #pragma unroll
        for (int it = 0; it < 2; ++it) {
            int task = tid + it * 256;
            int d = task & 127, sg = task >> 7;
            const float* vp = vg + (((size_t)(b * T_ + s0 + sg * 8) * NKV_) + kvh) * D_ + d;
            U8 pk;
            #pragma unroll
            for (int j = 0; j < 8; ++j) pk.us[j] = f2bf(vp[j * (NKV_ * D_)]);
            *(bf16x8*)(sVt + d * VSTR + sg * 8) = pk.v;
        }
        __syncthreads();

        f32x4 S0 = {0.f,0.f,0.f,0.f}, S1 = {0.f,0.f,0.f,0.f};
        #pragma unroll
        for (int c = 0; c < 4; ++c) {
            bf16x8 kh0 = *(const bf16x8*)(sKh + ln * KSTR + c * 32 + qd * 8);
            bf16x8 kh1 = *(const bf16x8*)(sKh + (16 + ln) * KSTR + c * 32 + qd * 8);
            bf16x8 kl0 = *(const bf16x8*)(sKl + ln * KSTR + c * 32 + qd * 8);
            bf16x8 kl1 = *(const bf16x8*)(sKl + (16 + ln) * KSTR + c * 32 + qd * 8);
            S0 = __builtin_amdgcn_mfma_f32_16x16x32_bf16(qh[c], kh0, S0, 0, 0, 0);
            S1 = __builtin_amdgcn_mfma_f32_16x16x32_bf16(qh[c], kh1, S1, 0, 0, 0);
            S0 = __builtin_amdgcn_mfma_f32_16x16x32_bf16(qh[c], kl0, S0, 0, 0, 0);
            S1 = __builtin_amdgcn_mfma_f32_16x16x32_bf16(qh[c], kl1, S1, 0, 0, 0);
            S0 = __builtin_amdgcn_mfma_f32_16x16x32_bf16(ql[c], kh0, S0, 0, 0, 0);
            S1 = __builtin_amdgcn_mfma_f32_16x16x32_bf16(ql[c], kh1, S1, 0, 0, 0);
        }
        const int ks0 = sb[s0 + ln];
        const int ks1 = sb[s0 + 16 + ln];
        float p0[4], p1[4], alpha[4];
        #pragma unroll
        for (int r = 0; r < 4; ++r) {
            const int trow = t0 + wave * 16 + qd * 4 + r;
            float s0v = ((s0 + ln <= trow) && (ks0 == qseg[r])) ? S0[r] : MASKV;
            float s1v = ((s0 + 16 + ln <= trow) && (ks1 == qseg[r])) ? S1[r] : MASKV;
            float mx = fmaxf(s0v, s1v);
            mx = fmaxf(mx, __shfl_xor(mx, 1));
            mx = fmaxf(mx, __shfl_xor(mx, 2));
            mx = fmaxf(mx, __shfl_xor(mx, 4));
            mx = fmaxf(mx, __shfl_xor(mx, 8));
            const float mn = fmaxf(m_prev[r], mx);
            alpha[r] = __expf(m_prev[r] - mn);
            p0[r] = __expf(s0v - mn);
            p1[r] = __expf(s1v - mn);
            l_lane[r] = alpha[r] * l_lane[r] + p0[r] + p1[r];
            m_prev[r] = mn;
        }
        #pragma unroll
        for (int i = 0; i < 8; ++i) {
            O[i][0] *= alpha[0]; O[i][1] *= alpha[1];
            O[i][2] *= alpha[2]; O[i][3] *= alpha[3];
        }
        {
            unsigned short* pw = sP[wave] + (qd * 4) * PSTR + ln;
            #pragma unroll
            for (int r = 0; r < 4; ++r) {
                pw[r * PSTR]      = f2bf(p0[r]);
                pw[r * PSTR + 16] = f2bf(p1[r]);
            }
        }
        asm volatile("s_waitcnt lgkmcnt(0)" ::: "memory");
        bf16x8 pa = *(const bf16x8*)(sP[wave] + ln * PSTR + qd * 8);
        #pragma unroll
        for (int sub = 0; sub < 8; ++sub) {
            bf16x8 bv = *(const bf16x8*)(sVt + (sub * 16 + ln) * VSTR + qd * 8);
            O[sub] = __builtin_amdgcn_mfma_f32_16x16x32_bf16(pa, bv, O[sub], 0, 0, 0);
        }
    }
    float inv[4];
    #pragma unroll
    for (int r = 0; r < 4; ++r) {
        float l = l_lane[r];
        l += __shfl_xor(l, 1);
        l += __shfl_xor(l, 2);
        l += __shfl_xor(l, 4);
        l += __shfl_xor(l, 8);
        inv[r] = 1.0f / l;
    }
    #pragma unroll
    for (int sub = 0; sub < 8; ++sub) {
        #pragma unroll
        for (int r = 0; r < 4; ++r) {
            const int trow = t0 + wave * 16 + qd * 4 + r;
            outg[(((size_t)(b * T_ + trow) * NQ_) + head) * D_ + sub * 16 + ln] =
                O[sub][r] * inv[r];
        }
    }
}

extern "C" void kernel_launch(void* const* d_in, const int* in_sizes, int n_in,
                              void* d_out, int out_size, void* d_ws, size_t ws_size,
                              hipStream_t stream) {
    const float* q  = (const float*)d_in[0];
    const float* k  = (const float*)d_in[1];
    const float* v  = (const float*)d_in[2];
    const int*   sg = (const int*)d_in[3];
    float*       o  = (float*)d_out;
    if (ws_size >= WS_NEED) {
        unsigned short* ws = (unsigned short*)d_ws;
        int* sstart = (int*)((char*)d_ws + WS_TILES_BYTES);
        prep<<<dim3(T_ / 32, NKV_, B_), dim3(256), 0, stream>>>(k, v, ws);
        prep_sstart<<<dim3(B_ * T_ / 256), dim3(256), 0, stream>>>(sg, sstart);
        attn_fwd<<<dim3(T_ / 128, NQ_, B_), dim3(256), 0, stream>>>(q, sstart, ws, o);
    } else {
        attn_fwd_fb<<<dim3(T_ / 64, NQ_, B_), dim3(256), 0, stream>>>(q, k, v, sg, o);
    }
}